// Round 10
// baseline (230.946 us; speedup 1.0000x reference)
//
#include <hip/hip_runtime.h>

// XCorrExt: B=32, S=160000, N=320, H=160, TAU=257, LAG_CUT=33
// out[b,f,tau-33] = 2*num/(e0 + e_tau + 1e-5), tau in [33,256]
// num[b,f,tau] = sum_n fr[n]*ext[tau+n]; fr[n] = xp[160f+n]
// ext[t] = xp[160f+t] (t<320) | xp[160f+t-160] (t>=320) | f=999,t>=320: x[t-320]
//
// R14: remap tau = 33 + t1 + 14*t0 (rows t1 in [0,14), cols t0 in [0,16)).
// A[t1][j] = fr[j - t1] (unit row shift -> K spread 13, K = 352 = 11 steps
// vs R12's 17) ; B[j][t0] = ext[33 + 14*t0 + j]. -35% inner DS data+MFMA.
//  - A misalignment (start = 32s+8q-col, 1-granular): padded per-frame copy
//    frP ([-16,352) halves, zeros outside frame support -> no zpad cndmask
//    and no neighbor-frame contamination), 2 parity copies (frP0/frP1).
//  - B always odd-parity -> reads the single sO shifted copy (as R12).
//  - fold crossing now lane-dependent: per-lane sA = (312-tb0)>>5 (last pA
//    step), sStr = (319-tb0)>>5 (bridge step, shadowed when no straddle);
//    bp = s<=sA ? pA : (s==sStr ? pbr : pB). Bridge = R12's ext[303..335).
//  - BLOCK=512 (8 waves, 1 frame/wave), LDS 30.3KB -> 4 blocks * 8 waves
//    = 32 waves/CU (R13 lesson: occupancy 24->36 waves was worth ~8us).
// R13 lesson applied: no instruction-flavor copies; this cuts DS *work*.

typedef _Float16 f16;
typedef _Float16 h8 __attribute__((ext_vector_type(8)));
typedef _Float16 h4 __attribute__((ext_vector_type(4)));
typedef float    f4 __attribute__((ext_vector_type(4)));

#define S_LEN 160000
#define FN    1000
#define NF    8
#define BLOCK 512
#define USZ   1536              // staged signal floats: 160*(NF-1)+416

// smem byte offsets (16B-aligned)
#define SH_OFF   0              // s_h: f16[1568] (zeros [1536,1568))
#define SO_OFF   3136           // sO:  dw[784], dw j = halves (s[2j-1], s[2j])
#define TH_OFF   6272           // T_h: f16[288] (zeros [256,288))
#define TO_OFF   6848           // TO:  dw[144]
#define BRO_OFF  7424           // brO: dw[8][16], dw j = ext halves (303+2j,304+2j)
#define FP0_OFF  7936           // frP0: dw[8][184], frame padded [-16,352), even
#define FP1_OFF  13824          // frP1: dw[8][184], odd parity
#define CSG_OFF  19712          // csg: f32[2048] (excl. prefix of s^2; zeros tail)
#define CST_OFF  27904          // csT: f32[260]
#define TOT_OFF  28944          // tot: f32[520] (512 + 8 wave sums)
#define SMEM_SZ  31024

__global__ __launch_bounds__(BLOCK)
void xcorr_kernel(const float* __restrict__ x, float* __restrict__ out) {
    __shared__ __align__(16) unsigned char smem[SMEM_SZ];
    f16*      s_h  = (f16*)(smem + SH_OFF);
    unsigned* sOd  = (unsigned*)(smem + SO_OFF);
    f16*      T_h  = (f16*)(smem + TH_OFF);
    unsigned* TOd  = (unsigned*)(smem + TO_OFF);
    unsigned* brOd = (unsigned*)(smem + BRO_OFF);
    unsigned* fp0  = (unsigned*)(smem + FP0_OFF);
    unsigned* fp1  = (unsigned*)(smem + FP1_OFF);
    float*    csg  = (float*)(smem + CSG_OFF);
    float*    csT  = (float*)(smem + CST_OFF);
    float*    tot  = (float*)(smem + TOT_OFF);
    f4*       csg4 = (f4*)csg;

    const int tid   = threadIdx.x;
    const int b     = blockIdx.y;
    const int fbase = blockIdx.x * NF;
    const long bOff = (long)b * S_LEN;
    const int gbase = fbase * 160;
    const bool lastBlk = (fbase + NF >= FN);

    // ---------------- P1: stage s_h (f16) + raw squares into csg --------------
    {
        const int i = 4 * tid;
        if (i < USZ) {
            const int gx = gbase + i;
            float v0, v1, v2, v3;
            if (gx + 3 < S_LEN) {
                const float4 v = *(const float4*)&x[bOff + gx];
                v0 = v.x; v1 = v.y; v2 = v.z; v3 = v.w;
            } else {
                v0 = (gx+0 < S_LEN) ? x[bOff+gx+0] : 0.f;
                v1 = (gx+1 < S_LEN) ? x[bOff+gx+1] : 0.f;
                v2 = (gx+2 < S_LEN) ? x[bOff+gx+2] : 0.f;
                v3 = (gx+3 < S_LEN) ? x[bOff+gx+3] : 0.f;
            }
            h4 hv; hv[0]=(f16)v0; hv[1]=(f16)v1; hv[2]=(f16)v2; hv[3]=(f16)v3;
            *(h4*)&s_h[i] = hv;
            f4 sq; sq[0]=v0*v0; sq[1]=v1*v1; sq[2]=v2*v2; sq[3]=v3*v3;
            csg4[tid] = sq;
        } else {
            f4 z; z[0]=z[1]=z[2]=z[3]=0.f;
            csg4[tid] = z;               // zeros csg [1536,2048)
        }
    }
    if (tid < 8) {                       // zero pad halves [1536,1568)
        h4 z; z[0]=(f16)0.f; z[1]=(f16)0.f; z[2]=(f16)0.f; z[3]=(f16)0.f;
        *(h4*)&s_h[1536 + 4*tid] = z;
    }
    if (lastBlk && tid < 288) {
        const float tv = (tid < 256) ? x[bOff + tid] : 0.f;
        T_h[tid] = (f16)tv;
        if (tid < 260) csT[tid] = tv * tv;
    }
    __syncthreads();

    // ---------------- P2: build sO, TO, frP0/1, brO; csg local prefix ---------
    {
        const unsigned* sd = (const unsigned*)s_h;       // 784 dwords
        for (int idx = tid; idx < 196; idx += BLOCK) {   // sO
            uint4 lo4;
            if (idx) lo4 = *(const uint4*)(sd + 4*idx - 4);
            else     { lo4.x=lo4.y=lo4.z=0u; lo4.w=0u; }
            const uint4 hi4 = *(const uint4*)(sd + 4*idx);
            uint4 o;
            o.x = __builtin_amdgcn_alignbit(hi4.x, lo4.w, 16);
            o.y = __builtin_amdgcn_alignbit(hi4.y, hi4.x, 16);
            o.z = __builtin_amdgcn_alignbit(hi4.z, hi4.y, 16);
            o.w = __builtin_amdgcn_alignbit(hi4.w, hi4.z, 16);
            *(uint4*)(sOd + 4*idx) = o;
        }
        if (lastBlk) {                   // TO: 144 dwords
            const unsigned* Td = (const unsigned*)T_h;
            for (int idx = tid; idx < 36; idx += BLOCK) {
                uint4 lo4;
                if (idx) lo4 = *(const uint4*)(Td + 4*idx - 4);
                else     { lo4.x=lo4.y=lo4.z=0u; lo4.w=0u; }
                const uint4 hi4 = *(const uint4*)(Td + 4*idx);
                uint4 o;
                o.x = __builtin_amdgcn_alignbit(hi4.x, lo4.w, 16);
                o.y = __builtin_amdgcn_alignbit(hi4.y, hi4.x, 16);
                o.z = __builtin_amdgcn_alignbit(hi4.z, hi4.y, 16);
                o.w = __builtin_amdgcn_alignbit(hi4.w, hi4.z, 16);
                *(uint4*)(TOd + 4*idx) = o;
            }
        }
        // frP0/frP1: 8 frames x 46 uint4 chunks each
        const uint4* sh4 = (const uint4*)s_h;
        for (int idx = tid; idx < 368; idx += BLOCK) {
            const int fi = idx / 46;
            const int c  = idx - 46*fi;          // chunk: dwords [4c, 4c+4)
            uint4 o0, o1;
            if (c < 2 || c > 42) {
                o0.x=o0.y=o0.z=0u; o0.w=0u; o1 = o0;
            } else if (c == 42) {                // frP0: zero; frP1: edge
                o0.x=o0.y=o0.z=0u; o0.w=0u;
                const unsigned prev = sd[80*fi + 159];   // halves (318,319)
                o1.x = __builtin_amdgcn_alignbit(0u, prev, 16); // (fr319, 0)
                o1.y = 0u; o1.z = 0u; o1.w = 0u;
            } else {
                const uint4 A = sh4[20*fi + c - 2];
                o0 = A;                          // frP0 interior copy
                const unsigned prev = (c == 2) ? 0u : sd[80*fi + 4*c - 9];
                o1.x = __builtin_amdgcn_alignbit(A.x, prev, 16);
                o1.y = __builtin_amdgcn_alignbit(A.y, A.x, 16);
                o1.z = __builtin_amdgcn_alignbit(A.z, A.y, 16);
                o1.w = __builtin_amdgcn_alignbit(A.w, A.z, 16);
            }
            *(uint4*)(fp0 + 184*fi + 4*c) = o0;
            *(uint4*)(fp1 + 184*fi + 4*c) = o1;
        }
        // brO: ext[303..335) per frame, shifted-pack
        if (tid < 128) {
            const int fi = tid >> 4, j = tid & 15;
            const bool lastF = lastBlk && (fbase + fi == FN-1);
            const int tl = 303 + 2*j, th = 304 + 2*j;
            const f16 lo = (tl < 320) ? s_h[160*fi + tl]
                          : (lastF ? T_h[tl-320] : s_h[160*fi + tl - 160]);
            const f16 hi = (th < 320) ? s_h[160*fi + th]
                          : (lastF ? T_h[th-320] : s_h[160*fi + th - 160]);
            union { struct { f16 a, c; } h; unsigned u; } pk;
            pk.h.a = lo; pk.h.c = hi;
            brOd[16*fi + j] = pk.u;
        }
    }
    float p[4]; float mytot;
    {
        const f4 v = csg4[tid];
        p[0] = 0.f;
        p[1] = v[0];
        p[2] = v[0] + v[1];
        p[3] = p[2] + v[2];
        mytot = p[3] + v[3];
        tot[tid] = mytot;
    }
    __syncthreads();

    // ---------------- P3: wave-local shfl scans + wave totals -----------------
    const int lane = tid & 63;
    const int wv   = tid >> 6;
    {
        const float v = tot[tid];
        float sc = v;
#pragma unroll
        for (int d = 1; d < 64; d <<= 1) {
            const float o = __shfl_up(sc, d);
            sc += (lane >= d) ? o : 0.f;
        }
        tot[tid] = sc - v;                      // exclusive within wave
        if (lane == 63) tot[512 + wv] = sc;     // wave total
        if (lastBlk && wv == 0) {               // exclusive scan of csT (260)
            float r[5]; float mt = 0.f;
#pragma unroll
            for (int e = 0; e < 5; ++e) {
                const int j = 5*lane + e;
                const float rv = (j < 260) ? csT[j] : 0.f;
                r[e] = mt; mt += rv;
            }
            float sc2 = mt;
#pragma unroll
            for (int d = 1; d < 64; d <<= 1) {
                const float o = __shfl_up(sc2, d);
                sc2 += (lane >= d) ? o : 0.f;
            }
            const float b2 = sc2 - mt;
#pragma unroll
            for (int e = 0; e < 5; ++e) {
                const int j = 5*lane + e;
                if (j < 260) csT[j] = b2 + r[e];
            }
        }
    }
    __syncthreads();

    // ---------------- P4: apply csg bases -------------------------------------
    {
        float wbase = 0.f;
#pragma unroll
        for (int w2 = 0; w2 < 7; ++w2)
            wbase += (wv > w2) ? tot[512 + w2] : 0.f;
        const float base = wbase + tot[tid];
        f4 o; o[0]=base+p[0]; o[1]=base+p[1]; o[2]=base+p[2]; o[3]=base+p[3];
        csg4[tid] = o;
    }
    __syncthreads();

    // ---------------- compute: wave wv -> frame fi = wv -----------------------
    const int col = lane & 15;           // C-col = t0 (tau stride 14)
    const int q   = lane >> 4;           // C-row block; t1 = 4q+v (tau stride 1)
    const int fi  = wv;
    const int f   = fbase + fi;
    const bool isLast = (f == FN-1);

    // A: fr[j - t1], padded copy; base dword (parity by col)
    const unsigned* ap = (col & 1)
        ? (fp1 + 184*fi + ((8*q - col + 17) >> 1))
        : (fp0 + 184*fi + ((8*q - col + 16) >> 1));
    // B: ext[tb0 + 32s + e], tb0 odd
    const int tb0 = 33 + 14*col + 8*q;          // [33, 267]
    const int j0  = (tb0 + 1) >> 1;
    const unsigned* pA  = sOd + 80*fi + j0;
    const unsigned* pB  = isLast ? (TOd + j0 - 160) : (pA - 80);
    const int sA   = (312 - tb0) >> 5;          // last all-below step (>=1)
    const int sStr = (319 - tb0) >> 5;          // bridge step (may be shadowed)
    const unsigned* pbr = brOd + 16*fi + ((tb0 + 32*sStr - 303) >> 1) - 16*sStr;

    f4 acc = {0.f, 0.f, 0.f, 0.f};
#pragma unroll
    for (int s = 0; s < 11; ++s) {
        const uint2 a0 = *(const uint2*)(ap + 16*s);
        const uint2 a1 = *(const uint2*)(ap + 16*s + 2);
        const unsigned* bp = (s <= sA) ? pA : ((s == sStr) ? pbr : pB);
        const uint2 b0 = *(const uint2*)(bp + 16*s);
        const uint2 b1 = *(const uint2*)(bp + 16*s + 2);
        union { unsigned u[4]; h8 h; } Af, Bf;
        Af.u[0] = a0.x; Af.u[1] = a0.y; Af.u[2] = a1.x; Af.u[3] = a1.y;
        Bf.u[0] = b0.x; Bf.u[1] = b0.y; Bf.u[2] = b1.x; Bf.u[3] = b1.y;
        acc = __builtin_amdgcn_mfma_f32_16x16x32_f16(Af.h, Bf.h, acc, 0, 0, 0);
    }

    // ---------------- epilogue: energies from exact-fp32 prefix sums ----------
    {
        const int D = 160*fi;
        const float c0   = csg[D];
        const float c160 = csg[D+160];
        const float c320 = csg[D+320];
        const float e0   = c320 - c0;
        float* op = &out[(long)(b*FN + f) * 224];
#pragma unroll
        for (int v = 0; v < 4; ++v) {
            const int t1 = 4*q + v;
            if (t1 <= 13) {
                const int tau = 33 + t1 + 14*col;
                const float et = isLast
                    ? (c320 - csg[D+tau] + csT[tau])
                    : (c320 - csg[D+tau] - c160 + csg[D+160+tau]);
                const float den = e0 + et + 1e-5f;
                op[t1 + 14*col] = 2.f * acc[v] * __builtin_amdgcn_rcpf(den);
            }
        }
    }
}

extern "C" void kernel_launch(void* const* d_in, const int* in_sizes, int n_in,
                              void* d_out, int out_size, void* d_ws, size_t ws_size,
                              hipStream_t stream) {
    const float* x = (const float*)d_in[0];
    float* out = (float*)d_out;
    dim3 grid(FN / NF, 32);              // (125, 32) = 4000 blocks, 512 thr
    dim3 block(BLOCK);
    hipLaunchKernelGGL(xcorr_kernel, grid, block, 0, stream, x, out);
}

// Round 11
// 86.340 us; speedup vs baseline: 2.6749x; 2.6749x over previous
//
#include <hip/hip_runtime.h>

// XCorrExt: B=32, S=160000, N=320, H=160, TAU=257, LAG_CUT=33
// out[b,f,tau-33] = 2*num/(e0 + e_tau + 1e-5), tau in [33,256]
// num[b,f,tau] = sum_n fr[n]*ext[tau+n]; fr[n] = xp[160f+n]
// ext[t] = xp[160f+t] (t<320) | xp[160f+t-160] (t>=320) | f=999,t>=320: x[t-320]
//
// R15 = R12 (best known: 91.0us) + shared-B inner loop.
// R14 post-mortem: uint2 LDS loads were 8B-MISALIGNED for half the lanes
// (dword parity fixed, b64 alignment not) -> DS slow-path serialization,
// all pipes idle, 2x regression. Lesson: scalar b32 LDS reads only
// (compiler fuses to ds_read2_b32, which needs just 4B alignment).
// R15's one change: a wave's two frames {g=2wv, h=g+1} read B from ONE
// arithmetic progression pS+16u (pB = pA-80, pA_h = pA_g+80):
//   u in [0,8)  -> frame g regionA (s=u)
//   u in [4,12) -> frame g regionB (s=u+5)
//   u in [5,13) -> frame h regionA (s=u-5)
//   u in [9,17) -> frame h regionB (s=u)       [skip if h==999 -> TOd tail]
// 17 unique frags + 2 straddles vs R12's 36 -> DS instrs/wave ~106 -> ~72.
// All u-ranges compile-time; per-lane fold stays in R12's p8/bridge logic.
// R12 recap: 16x16x544 Toeplitz GEMM/frame (mfma_f32_16x16x32_f16), A from
// s_h (b128-aligned), fp32 energies via hierarchical block prefix sums.

typedef _Float16 f16;
typedef _Float16 h8 __attribute__((ext_vector_type(8)));
typedef _Float16 h4 __attribute__((ext_vector_type(4)));
typedef float    f4 __attribute__((ext_vector_type(4)));

#define S_LEN 160000
#define FN    1000
#define NF    8
#define BLOCK 256
#define USZ   1536              // staged signal floats: 160*(NF-1)+416

// smem byte offsets (all 16B-aligned)
#define ZPAD_OFF 0              // 16B zeros (A-frag OOB target)
#define SE_OFF   16             // s_h: f16[1568] (zero pad [1536,1568))
#define SO_OFF   3152           // sO:  dword[784], dw j = halves (2j-1, 2j)
#define TH_OFF   6288           // T_h: f16[288] (zero pad [256,288))
#define TO_OFF   6864           // TO:  dword[144]
#define BRE_OFF  7440           // brE: f16[8][32]  = ext[304..336) per frame
#define BRO_OFF  7952           // brO: dword[8][16], dw j = ext halves (303+2j, 304+2j)
#define CSG_OFF  8464           // csg: float[1552] (excl. prefix of s^2)
#define CST_OFF  14672          // csT: float[260]
#define TOT_OFF  15712          // tot: float[260] (256 + wave sums)
#define SMEM_SZ  16752

__global__ __launch_bounds__(BLOCK)
void xcorr_kernel(const float* __restrict__ x, float* __restrict__ out) {
    __shared__ __align__(16) unsigned char smem[SMEM_SZ];
    f16*      zpad = (f16*)(smem + ZPAD_OFF);
    f16*      s_h  = (f16*)(smem + SE_OFF);
    unsigned* sOd  = (unsigned*)(smem + SO_OFF);
    f16*      T_h  = (f16*)(smem + TH_OFF);
    unsigned* TOd  = (unsigned*)(smem + TO_OFF);
    f16*      brE  = (f16*)(smem + BRE_OFF);
    unsigned* brOd = (unsigned*)(smem + BRO_OFF);
    float*    csg  = (float*)(smem + CSG_OFF);
    float*    csT  = (float*)(smem + CST_OFF);
    float*    tot  = (float*)(smem + TOT_OFF);

    const int tid   = threadIdx.x;
    const int b     = blockIdx.y;
    const int fbase = blockIdx.x * NF;
    const long bOff = (long)b * S_LEN;
    const int gbase = fbase * 160;
    const bool lastBlk = (fbase + NF >= FN);

    // ---------------- P1: stage s_h (f16) + raw squares into csg --------------
    for (int i = 4*tid; i < USZ; i += 4*BLOCK) {
        const int gx = gbase + i;
        float v0, v1, v2, v3;
        if (gx + 3 < S_LEN) {
            const float4 v = *(const float4*)&x[bOff + gx];
            v0 = v.x; v1 = v.y; v2 = v.z; v3 = v.w;
        } else {
            v0 = (gx+0 < S_LEN) ? x[bOff+gx+0] : 0.f;
            v1 = (gx+1 < S_LEN) ? x[bOff+gx+1] : 0.f;
            v2 = (gx+2 < S_LEN) ? x[bOff+gx+2] : 0.f;
            v3 = (gx+3 < S_LEN) ? x[bOff+gx+3] : 0.f;
        }
        h4 hv; hv[0]=(f16)v0; hv[1]=(f16)v1; hv[2]=(f16)v2; hv[3]=(f16)v3;
        *(h4*)&s_h[i] = hv;
        f4 sq; sq[0]=v0*v0; sq[1]=v1*v1; sq[2]=v2*v2; sq[3]=v3*v3;
        *(f4*)&csg[i] = sq;
    }
    if (tid < 8) {                       // zero pad halves [1536,1568)
        h4 z; z[0]=(f16)0.f; z[1]=(f16)0.f; z[2]=(f16)0.f; z[3]=(f16)0.f;
        *(h4*)&s_h[1536 + 4*tid] = z;
    }
    if (tid < 16) csg[1536 + tid] = 0.f;
    if (tid == 0) { uint4 z; z.x=z.y=z.z=z.w=0u; *(uint4*)(smem + ZPAD_OFF) = z; }
    if (lastBlk) {
        for (int j = tid; j < 288; j += BLOCK) {
            const float tv = (j < 256) ? x[bOff + j] : 0.f;
            T_h[j] = (f16)tv;
            if (j < 260) csT[j] = tv * tv;
        }
    }
    __syncthreads();

    // ---------------- P2: build sO (+TO) + bridge; csg local prefix -----------
    {
        const unsigned* sEd = (const unsigned*)s_h;     // 784 dwords
        for (int idx = tid; idx < 196; idx += BLOCK) {
            uint4 lo4;
            if (idx) lo4 = *(const uint4*)(sEd + 4*idx - 4);
            else     { lo4.x=lo4.y=lo4.z=0u; lo4.w=0u; }
            const uint4 hi4 = *(const uint4*)(sEd + 4*idx);
            uint4 o;
            o.x = __builtin_amdgcn_alignbit(hi4.x, lo4.w, 16);
            o.y = __builtin_amdgcn_alignbit(hi4.y, hi4.x, 16);
            o.z = __builtin_amdgcn_alignbit(hi4.z, hi4.y, 16);
            o.w = __builtin_amdgcn_alignbit(hi4.w, hi4.z, 16);
            *(uint4*)(sOd + 4*idx) = o;
        }
        if (lastBlk) {                   // TO: 144 dwords
            const unsigned* Td = (const unsigned*)T_h;
            for (int idx = tid; idx < 36; idx += BLOCK) {
                uint4 lo4;
                if (idx) lo4 = *(const uint4*)(Td + 4*idx - 4);
                else     { lo4.x=lo4.y=lo4.z=0u; lo4.w=0u; }
                const uint4 hi4 = *(const uint4*)(Td + 4*idx);
                uint4 o;
                o.x = __builtin_amdgcn_alignbit(hi4.x, lo4.w, 16);
                o.y = __builtin_amdgcn_alignbit(hi4.y, hi4.x, 16);
                o.z = __builtin_amdgcn_alignbit(hi4.z, hi4.y, 16);
                o.w = __builtin_amdgcn_alignbit(hi4.w, hi4.z, 16);
                *(uint4*)(TOd + 4*idx) = o;
            }
        }
        // bridge: ext[304..336) per frame (contiguous across the t=320 fold)
        {
            const int fi = tid >> 5, j = tid & 31;      // 256 threads exactly
            const int t = 304 + j;
            const bool lastF = lastBlk && (fbase + fi == FN-1);
            f16 v;
            if (t < 320)      v = s_h[160*fi + t];
            else if (lastF)   v = T_h[t - 320];
            else              v = s_h[160*fi + t - 160];
            brE[32*fi + j] = v;
        }
        if (tid < NF*16) {                              // 128 threads
            const int fi = tid >> 4, j = tid & 15;
            const int tl = 303 + 2*j, th = 304 + 2*j;
            const bool lastF = lastBlk && (fbase + fi == FN-1);
            const f16 lo = (tl < 320) ? s_h[160*fi + tl]
                          : (lastF ? T_h[tl-320] : s_h[160*fi + tl - 160]);
            const f16 hi = (th < 320) ? s_h[160*fi + th]
                          : (lastF ? T_h[th-320] : s_h[160*fi + th - 160]);
            union { struct { f16 a, c; } h; unsigned u; } pk;
            pk.h.a = lo; pk.h.c = hi;
            brOd[16*fi + j] = pk.u;
        }
    }
    float p[7]; float mytot = 0.f;
    {
        const int t0 = 7*tid;
#pragma unroll
        for (int e = 0; e < 7; ++e) {
            const float r = (t0+e < 1552) ? csg[t0+e] : 0.f;
            p[e] = mytot;                       // exclusive within thread
            mytot += r;
        }
        tot[tid] = mytot;
    }
    __syncthreads();

    // ---------------- P3: all-wave scan (wave-local shfl + wave totals) -------
    const int lane = tid & 63;
    const int wv   = tid >> 6;
    {
        const float v = tot[tid];
        float sc = v;
#pragma unroll
        for (int d = 1; d < 64; d <<= 1) {
            const float o = __shfl_up(sc, d);
            sc += (lane >= d) ? o : 0.f;
        }
        tot[tid] = sc - v;                      // exclusive within wave
        if (lane == 63) tot[256 + wv] = sc;     // wave total
        if (lastBlk && wv == 0) {               // exclusive scan of csT (260)
            float r[5]; float mt = 0.f;
#pragma unroll
            for (int e = 0; e < 5; ++e) {
                const int j = 5*lane + e;
                const float rv = (j < 260) ? csT[j] : 0.f;
                r[e] = mt; mt += rv;
            }
            float sc2 = mt;
#pragma unroll
            for (int d = 1; d < 64; d <<= 1) {
                const float o = __shfl_up(sc2, d);
                sc2 += (lane >= d) ? o : 0.f;
            }
            const float b2 = sc2 - mt;
#pragma unroll
            for (int e = 0; e < 5; ++e) {
                const int j = 5*lane + e;
                if (j < 260) csT[j] = b2 + r[e];
            }
        }
    }
    __syncthreads();

    // ---------------- P4: apply csg bases (exclusive prefix complete) ---------
    {
        const float w1 = tot[256], w2 = tot[257], w3 = tot[258];
        const float wbase = ((wv > 0) ? w1 : 0.f) + ((wv > 1) ? w2 : 0.f)
                          + ((wv > 2) ? w3 : 0.f);
        const float base = wbase + tot[tid];
        const int t0 = 7*tid;
#pragma unroll
        for (int e = 0; e < 7; ++e)
            if (t0+e < 1552) csg[t0+e] = base + p[e];
    }
    __syncthreads();

    // ---------------- compute: wave wv -> frames g=2wv, h=g+1 -----------------
    const int col  = lane & 15;          // A-row t1-lane, B-col t0, C-col
    const int q    = lane >> 4;          // k-group; C-row = 4q+v
    const int off0 = 8*q - 16*col;       // A: off = j - 16*row, j = 32s+8q
    const int tb0  = 33 + col + 8*q;     // B: half index base into ext, [33,72]
    const int pc   = tb0 & 1;
    const unsigned* bbS = pc ? sOd : (const unsigned*)s_h;
    const unsigned* bbT = pc ? TOd : (const unsigned*)T_h;

    const int g = 2*wv, h = g + 1;
    const int fg = fbase + g, fh = fbase + h;
    const bool isLastH = (fh == FN-1);   // only the odd frame can be 999
    const f16* frg = s_h + 160*g;
    const f16* frh = s_h + 160*h;
    const int j0 = (tb0 + pc) >> 1;
    const unsigned* pS  = bbS + 80*g + j0;   // shared B base: frag(u) = pS+16u
    const unsigned* pTB = bbT + ((tb0 - 320 + pc) >> 1);   // deref'd only if isLastH
    // straddle (s=8) pointers, per R12: frag read at p8 + 128
    const unsigned* brBg = pc ? (brOd + 16*g) : ((const unsigned*)brE + 16*g);
    const unsigned* brBh = pc ? (brOd + 16*h) : ((const unsigned*)brE + 16*h);
    const unsigned* pBh  = isLastH ? pTB : pS;
    const unsigned* p8g  = (tb0 <= 56) ? pS
                         : ((tb0 <= 63) ? (brBg + ((tb0 - 48 + pc) >> 1) - 128)
                                        : (pS - 80));
    const unsigned* p8h  = (tb0 <= 56) ? (pS + 80)
                         : ((tb0 <= 63) ? (brBh + ((tb0 - 48 + pc) >> 1) - 128)
                                        : pBh);

    auto ALOAD = [&](const f16* frm, int s_) -> h8 {
        const int off_ = off0 + 32*s_;
        const f16* ap_ = ((unsigned)off_ <= 312u) ? (frm + off_) : zpad;
        return *(const h8*)ap_;
    };
    auto BLOAD = [&](const unsigned* bp, int o) -> h8 {
        union { unsigned u[4]; h8 hh; } B_;
        B_.u[0] = bp[o+0]; B_.u[1] = bp[o+1];   // scalar b32 only: 4B-safe,
        B_.u[2] = bp[o+2]; B_.u[3] = bp[o+3];   // compiler fuses to read2_b32
        return B_.hh;
    };

    f4 accg = {0.f, 0.f, 0.f, 0.f};
    f4 acch = {0.f, 0.f, 0.f, 0.f};
#pragma unroll
    for (int u = 0; u < 17; ++u) {
        const h8 F = BLOAD(pS, 16*u);
        if (u <= 7)
            accg = __builtin_amdgcn_mfma_f32_16x16x32_f16(ALOAD(frg, u),   F, accg, 0, 0, 0);
        if (u >= 4 && u <= 11)
            accg = __builtin_amdgcn_mfma_f32_16x16x32_f16(ALOAD(frg, u+5), F, accg, 0, 0, 0);
        if (u >= 5 && u <= 12)
            acch = __builtin_amdgcn_mfma_f32_16x16x32_f16(ALOAD(frh, u-5), F, acch, 0, 0, 0);
        if (u >= 9 && !isLastH)          // wave-uniform guard
            acch = __builtin_amdgcn_mfma_f32_16x16x32_f16(ALOAD(frh, u),   F, acch, 0, 0, 0);
    }
    // straddle step s=8 for both frames (per-lane pA/bridge/pB via p8)
    accg = __builtin_amdgcn_mfma_f32_16x16x32_f16(ALOAD(frg, 8), BLOAD(p8g, 128), accg, 0, 0, 0);
    acch = __builtin_amdgcn_mfma_f32_16x16x32_f16(ALOAD(frh, 8), BLOAD(p8h, 128), acch, 0, 0, 0);
    if (isLastH) {                       // frame 999 regionB reads T (rare wave)
#pragma unroll
        for (int s = 9; s < 17; ++s)
            acch = __builtin_amdgcn_mfma_f32_16x16x32_f16(ALOAD(frh, s), BLOAD(pTB, 16*s), acch, 0, 0, 0);
    }

    // ---------------- epilogue: energies from exact-fp32 prefix sums ----------
    {   // frame g (even fi: never the last frame)
        const int D = 160*g;
        const float c0   = csg[D];
        const float c160 = csg[D+160];
        const float c320 = csg[D+320];
        const float e0   = c320 - c0;
        float* op = &out[(long)(b*FN + fg) * 224];
#pragma unroll
        for (int v = 0; v < 4; ++v) {
            const int t1 = 4*q + v;
            if (t1 <= 13) {
                const int tau = 33 + 16*t1 + col;
                const float et = c320 - csg[D+tau] - c160 + csg[D+160+tau];
                const float den = e0 + et + 1e-5f;
                op[tau - 33] = 2.f * accg[v] * __builtin_amdgcn_rcpf(den);
            }
        }
    }
    {   // frame h
        const int D = 160*h;
        const float c0   = csg[D];
        const float c160 = csg[D+160];
        const float c320 = csg[D+320];
        const float e0   = c320 - c0;
        float* op = &out[(long)(b*FN + fh) * 224];
#pragma unroll
        for (int v = 0; v < 4; ++v) {
            const int t1 = 4*q + v;
            if (t1 <= 13) {
                const int tau = 33 + 16*t1 + col;
                const float et = isLastH
                    ? (c320 - csg[D+tau] + csT[tau])
                    : (c320 - csg[D+tau] - c160 + csg[D+160+tau]);
                const float den = e0 + et + 1e-5f;
                op[tau - 33] = 2.f * acch[v] * __builtin_amdgcn_rcpf(den);
            }
        }
    }
}

extern "C" void kernel_launch(void* const* d_in, const int* in_sizes, int n_in,
                              void* d_out, int out_size, void* d_ws, size_t ws_size,
                              hipStream_t stream) {
    const float* x = (const float*)d_in[0];
    float* out = (float*)d_out;
    dim3 grid(FN / NF, 32);              // (125, 32) = 4000 blocks
    dim3 block(BLOCK);
    hipLaunchKernelGGL(xcorr_kernel, grid, block, 0, stream, x, out);
}